// Round 3
// baseline (1277.126 us; speedup 1.0000x reference)
//
#include <hip/hip_runtime.h>

#define B   64
#define IC  2048
#define ID  16
#define DD  256
#define GB  8     // batches per u-group
#define KS  8     // K-chunks in c_kernel (K=256 per block)
#define NSQ 11    // matrix squarings
#define NPI 7     // finish matvecs: total exponent 2^11 * 8 = 16384

// ws layout (float offsets):
//  U   : GB*IC*DD = 4,194,304  @ 0
//  C   : B*DD*DD  = 4,194,304  @ 4,194,304
//  Sc  : 2,048               @ 8,388,608
//  E/P : 4,194,304            @ 8,390,656   (P overlays E; P dead before sq)
//  total ~50.3 MB (same footprint as round 2)

// ---------------- stage 1: u[b,c,:] = x[b,c,:] @ W_c ----------------
__global__ void u_kernel(const float* __restrict__ caps,
                         const float* __restrict__ W,
                         float* __restrict__ U, int b0) {
    const int c = blockIdx.x;
    const int t = threadIdx.x;
    __shared__ float xs[GB][ID];
    if (t < GB * ID)
        xs[t / ID][t % ID] = caps[(((size_t)(b0 + t / ID)) * IC + c) * ID + (t % ID)];
    __syncthreads();
    float acc[GB];
#pragma unroll
    for (int bb = 0; bb < GB; ++bb) acc[bb] = 0.f;
#pragma unroll
    for (int i = 0; i < ID; ++i) {
        float w = W[((size_t)c * ID + i) * DD + t];
#pragma unroll
        for (int bb = 0; bb < GB; ++bb) acc[bb] = fmaf(xs[bb][i], w, acc[bb]);
    }
#pragma unroll
    for (int bb = 0; bb < GB; ++bb)
        U[((size_t)bb * IC + c) * DD + t] = acc[bb];
}

// -------- stage 2a: partial C tiles, K=256 per block, 64-row LDS chunks -----
__global__ __launch_bounds__(256) void c_kernel(const float* __restrict__ U,
                                                float* __restrict__ P) {
    const int tile = blockIdx.x;           // 0..15
    const int bb   = blockIdx.y;           // batch in group
    const int kch  = blockIdx.z;           // 0..KS-1
    const int d0 = (tile >> 2) * 64, e0 = (tile & 3) * 64;
    const int t  = threadIdx.x;
    const int rs = t >> 4, cs = (t & 15) * 4;   // staging map
    const int td = t >> 4, te = t & 15;         // compute map
    __shared__ float Ad[64][64];
    __shared__ float Ae[64][64];
    float acc[4][4] = {};
    const float* Ub = U + (size_t)bb * IC * DD;
    const int k0 = kch * (IC / KS);
#pragma unroll
    for (int ch = 0; ch < 4; ++ch) {
        const int kb = k0 + ch * 64;
        float4 a[4], b[4];
#pragma unroll
        for (int p = 0; p < 4; ++p) {
            a[p] = *(const float4*)&Ub[((size_t)(kb + p * 16 + rs)) * DD + d0 + cs];
            b[p] = *(const float4*)&Ub[((size_t)(kb + p * 16 + rs)) * DD + e0 + cs];
        }
        __syncthreads();
#pragma unroll
        for (int p = 0; p < 4; ++p) {
            *(float4*)&Ad[p * 16 + rs][cs] = a[p];
            *(float4*)&Ae[p * 16 + rs][cs] = b[p];
        }
        __syncthreads();
#pragma unroll 8
        for (int k = 0; k < 64; ++k) {
            float4 a4 = *(const float4*)&Ad[k][4 * td];
            float4 b4 = *(const float4*)&Ae[k][4 * te];
            float ar[4] = {a4.x, a4.y, a4.z, a4.w};
            float br[4] = {b4.x, b4.y, b4.z, b4.w};
#pragma unroll
            for (int i = 0; i < 4; ++i)
#pragma unroll
                for (int j = 0; j < 4; ++j)
                    acc[i][j] = fmaf(ar[i], br[j], acc[i][j]);
        }
    }
    float* Pt = P + ((size_t)(kch * GB + bb) * 16 + tile) * 4096;
#pragma unroll
    for (int i = 0; i < 4; ++i) {
        float4 o = make_float4(acc[i][0], acc[i][1], acc[i][2], acc[i][3]);
        *(float4*)&Pt[(size_t)(4 * td + i) * 64 + 4 * te] = o;
    }
}

// -------- stage 2b: sum KS partials -> C, fused trace -> Sc0 ----------------
__global__ void reduce_kernel(const float* __restrict__ P,
                              float* __restrict__ C,
                              float* __restrict__ Sc0, int b0) {
    const int tile = blockIdx.x;
    const int bb   = blockIdx.y;
    const int d0 = (tile >> 2) * 64, e0 = (tile & 3) * 64;
    const int t = threadIdx.x;
    float* Cb = C + (size_t)(b0 + bb) * DD * DD;
    float tsum = 0.f;
#pragma unroll
    for (int p = 0; p < 4; ++p) {
        const int idx = p * 1024 + 4 * t;
        float4 s = make_float4(0.f, 0.f, 0.f, 0.f);
#pragma unroll
        for (int kch = 0; kch < KS; ++kch) {
            const float4 v = *(const float4*)&P[((size_t)(kch * GB + bb) * 16 + tile) * 4096 + idx];
            s.x += v.x; s.y += v.y; s.z += v.z; s.w += v.w;
        }
        const int l = idx >> 6, c0 = idx & 63;
        *(float4*)&Cb[(size_t)(d0 + l) * DD + e0 + c0] = s;
        if (d0 == e0) {
            if (c0 + 0 == l) tsum += s.x;
            if (c0 + 1 == l) tsum += s.y;
            if (c0 + 2 == l) tsum += s.z;
            if (c0 + 3 == l) tsum += s.w;
        }
    }
    if (d0 == e0) {
        __shared__ float red[256];
        red[t] = tsum;
        __syncthreads();
        for (int s = 128; s > 0; s >>= 1) {
            if (t < s) red[t] += red[t + s];
            __syncthreads();
        }
        if (t == 0) atomicAdd(&Sc0[b0 + bb], red[0]);
    }
}

// ---------------- E = (D/s)^2 with fused trace(E) -> s_out ----------------
__global__ __launch_bounds__(256) void sq_kernel(const float* __restrict__ Dm,
                                                 float* __restrict__ E,
                                                 const float* __restrict__ s_in,
                                                 float* __restrict__ s_out) {
    const int tile = blockIdx.x;
    const int b    = blockIdx.y;
    const int d0 = (tile >> 2) * 64, e0 = (tile & 3) * 64;
    const int t  = threadIdx.x;
    const int rs = t >> 4, cs = (t & 15) * 4;
    const int td = t >> 4, te = t & 15;
    __shared__ float Ad[64][64];
    __shared__ float Ae[64][64];
    float acc[4][4] = {};
    const float* Db = Dm + (size_t)b * DD * DD;
    const float s = s_in[b];
    const float inv = 1.f / (s * s);
#pragma unroll
    for (int ch = 0; ch < 4; ++ch) {
        const int kb = ch * 64;
        float4 a[4], b4r[4];
#pragma unroll
        for (int p = 0; p < 4; ++p) {
            a[p]   = *(const float4*)&Db[((size_t)(kb + p * 16 + rs)) * DD + d0 + cs];
            b4r[p] = *(const float4*)&Db[((size_t)(kb + p * 16 + rs)) * DD + e0 + cs];
        }
        __syncthreads();
#pragma unroll
        for (int p = 0; p < 4; ++p) {
            *(float4*)&Ad[p * 16 + rs][cs] = a[p];
            *(float4*)&Ae[p * 16 + rs][cs] = b4r[p];
        }
        __syncthreads();
#pragma unroll 8
        for (int k = 0; k < 64; ++k) {
            float4 a4 = *(const float4*)&Ad[k][4 * td];
            float4 b4 = *(const float4*)&Ae[k][4 * te];
            float ar[4] = {a4.x, a4.y, a4.z, a4.w};
            float br[4] = {b4.x, b4.y, b4.z, b4.w};
#pragma unroll
            for (int i = 0; i < 4; ++i)
#pragma unroll
                for (int j = 0; j < 4; ++j)
                    acc[i][j] = fmaf(ar[i], br[j], acc[i][j]);
        }
    }
#pragma unroll
    for (int i = 0; i < 4; ++i)
#pragma unroll
        for (int j = 0; j < 4; ++j)
            acc[i][j] *= inv;
    float* Eb = E + (size_t)b * DD * DD;
#pragma unroll
    for (int i = 0; i < 4; ++i) {
        float4 o = make_float4(acc[i][0], acc[i][1], acc[i][2], acc[i][3]);
        *(float4*)&Eb[(size_t)(d0 + 4 * td + i) * DD + e0 + 4 * te] = o;
    }
    if (d0 == e0 && td == te)
        atomicAdd(&s_out[b], acc[0][0] + acc[1][1] + acc[2][2] + acc[3][3]);
}

// ------- finish: column start + NPI matvecs (no renorm; lambda1 ~ 1) --------
__global__ void finish_kernel(const float* __restrict__ Dm, float* __restrict__ out) {
    const int b = blockIdx.x, t = threadIdx.x;
    const float* Db = Dm + (size_t)b * DD * DD;
    __shared__ float vs[DD];
    __shared__ float red[DD];
    __shared__ int   ridx[DD];
    red[t] = Db[(size_t)t * DD + t];
    ridx[t] = t;
    __syncthreads();
    for (int s = 128; s > 0; s >>= 1) {
        if (t < s && red[t + s] > red[t]) { red[t] = red[t + s]; ridx[t] = ridx[t + s]; }
        __syncthreads();
    }
    const int jmax0 = ridx[0];
    __syncthreads();
    float v = Db[(size_t)jmax0 * DD + t];   // symmetric: column == row
    for (int it = 0; it < NPI; ++it) {
        vs[t] = v;
        __syncthreads();
        float a = 0.f;
        const float* row = Db + (size_t)t * DD;
#pragma unroll 8
        for (int j = 0; j < DD; j += 4) {
            float4 d4 = *(const float4*)&row[j];
            a = fmaf(d4.x, vs[j], a);
            a = fmaf(d4.y, vs[j + 1], a);
            a = fmaf(d4.z, vs[j + 2], a);
            a = fmaf(d4.w, vs[j + 3], a);
        }
        __syncthreads();          // all reads of vs done before next overwrite
        v = a;
    }
    // final: normalize + sign-fix at argmax|v|
    vs[t] = v;
    red[t] = v * v;
    __syncthreads();
    for (int s = 128; s > 0; s >>= 1) {
        if (t < s) red[t] += red[t + s];
        __syncthreads();
    }
    const float nrm = sqrtf(red[0]);
    __syncthreads();
    red[t] = fabsf(v);
    ridx[t] = t;
    __syncthreads();
    for (int s = 128; s > 0; s >>= 1) {
        if (t < s && red[t + s] > red[t]) { red[t] = red[t + s]; ridx[t] = ridx[t + s]; }
        __syncthreads();
    }
    const float sgn = (vs[ridx[0]] < 0.f) ? -1.f : 1.f;
    out[(size_t)b * DD + t] = sgn * v / nrm;
}

extern "C" void kernel_launch(void* const* d_in, const int* in_sizes, int n_in,
                              void* d_out, int out_size, void* d_ws, size_t ws_size,
                              hipStream_t stream) {
    const float* caps = (const float*)d_in[0];   // (64, 2048, 16)
    const float* W    = (const float*)d_in[1];   // (2048, 16, 256)
    float* out = (float*)d_out;                  // (64, 256)
    float* ws  = (float*)d_ws;

    float* U  = ws;
    float* Cb = ws + 4194304;
    float* Sc = ws + 8388608;    // (NSQ+1) slots of 64 floats
    float* Eb = ws + 8390656;    // also serves as partial buffer P

    hipMemsetAsync(Sc, 0, 2048 * sizeof(float), stream);

    // stages 1+2: per 8-batch group; c partials into P (=Eb), reduce into C
    for (int g = 0; g < 8; ++g) {
        u_kernel<<<IC, 256, 0, stream>>>(caps, W, U, g * GB);
        c_kernel<<<dim3(16, GB, KS), 256, 0, stream>>>(U, Eb);
        reduce_kernel<<<dim3(16, GB), 256, 0, stream>>>(Eb, Cb, Sc, g * GB);
    }

    // eigen: NSQ trace-normalized squarings (trace fused into producer)
    float* ping = Cb;
    float* pong = Eb;
    for (int it = 0; it < NSQ; ++it) {
        sq_kernel<<<dim3(16, B), 256, 0, stream>>>(ping, pong, Sc + it * 64, Sc + (it + 1) * 64);
        float* tmp = ping; ping = pong; pong = tmp;
    }

    finish_kernel<<<B, 256, 0, stream>>>(ping, out);
}

// Round 4
// 1043.888 us; speedup vs baseline: 1.2234x; 1.2234x over previous
//
#include <hip/hip_runtime.h>

#define NB  64
#define IC  2048
#define ID  16
#define DD  256
#define NSQ 11    // matrix squarings
#define NPI 7     // finish matvecs: exponent 2^11 * 8 = 16384 (verified R3)

// ---------------- stage 1: u[b,c,:] = x[b,c,:] @ W_c (all GBATCH batches) ---
template<int GBATCH>
__global__ __launch_bounds__(256) void u_kernel(const float* __restrict__ caps,
                                                const float* __restrict__ W,
                                                float* __restrict__ U, int b0) {
    const int c = blockIdx.x;
    const int t = threadIdx.x;
    __shared__ float xsT[ID][GBATCH];     // transposed: float4 reads over b
    if (t < GBATCH * 4) {
        const int b = t >> 2, q = (t & 3) * 4;
        const float4 x4 = *(const float4*)&caps[((size_t)(b0 + b) * IC + c) * ID + q];
        xsT[q + 0][b] = x4.x; xsT[q + 1][b] = x4.y;
        xsT[q + 2][b] = x4.z; xsT[q + 3][b] = x4.w;
    }
    float w[ID];
#pragma unroll
    for (int i = 0; i < ID; ++i) w[i] = W[((size_t)c * ID + i) * DD + t];
    __syncthreads();
    float acc[GBATCH] = {};
#pragma unroll 4
    for (int i = 0; i < ID; ++i) {
#pragma unroll
        for (int bq = 0; bq < GBATCH / 4; ++bq) {
            const float4 xv = *(const float4*)&xsT[i][4 * bq];
            acc[4 * bq + 0] = fmaf(xv.x, w[i], acc[4 * bq + 0]);
            acc[4 * bq + 1] = fmaf(xv.y, w[i], acc[4 * bq + 1]);
            acc[4 * bq + 2] = fmaf(xv.z, w[i], acc[4 * bq + 2]);
            acc[4 * bq + 3] = fmaf(xv.w, w[i], acc[4 * bq + 3]);
        }
    }
#pragma unroll
    for (int b = 0; b < GBATCH; ++b)
        U[((size_t)b * IC + c) * DD + t] = acc[b];
}

// ------- stage 2: C_b = U_b^T U_b, 128x128 tile, 8x8 micro, K=2048 ----------
// blockId = tile*gbatch + bb  ->  blockId%8 == bb%8 : tiles of a batch co-XCD
__global__ __launch_bounds__(256) void c_kernel(const float* __restrict__ U,
                                                float* __restrict__ C,
                                                float* __restrict__ Sc,
                                                int b0, int bmask, int bshift) {
    const int id   = blockIdx.x;
    const int bb   = id & bmask;
    const int tile = id >> bshift;
    const int d0 = (tile >> 1) * 128, e0 = (tile & 1) * 128;
    const int t  = threadIdx.x;
    const int td = t >> 4, te = t & 15;
    const int sr = t >> 5, sc4 = (t & 31) * 4;
    __shared__ float Ad[32][128];
    __shared__ float Ae[32][128];
    __shared__ float red[256];
    float acc[8][8] = {};
    const float* Ub = U + (size_t)bb * IC * DD;
    for (int kb = 0; kb < IC; kb += 32) {
        float4 ra[4], rb[4];
#pragma unroll
        for (int p = 0; p < 4; ++p) {
            const size_t row = (size_t)(kb + p * 8 + sr) * DD;
            ra[p] = *(const float4*)&Ub[row + d0 + sc4];
            rb[p] = *(const float4*)&Ub[row + e0 + sc4];
        }
        __syncthreads();
#pragma unroll
        for (int p = 0; p < 4; ++p) {
            *(float4*)&Ad[p * 8 + sr][sc4] = ra[p];
            *(float4*)&Ae[p * 8 + sr][sc4] = rb[p];
        }
        __syncthreads();
#pragma unroll 4
        for (int k = 0; k < 32; ++k) {
            const float4 a0 = *(const float4*)&Ad[k][8 * td];
            const float4 a1 = *(const float4*)&Ad[k][8 * td + 4];
            const float4 g0 = *(const float4*)&Ae[k][4 * te];        // 2-way: free
            const float4 g1 = *(const float4*)&Ae[k][64 + 4 * te];
            const float av[8] = {a0.x, a0.y, a0.z, a0.w, a1.x, a1.y, a1.z, a1.w};
            const float bv[8] = {g0.x, g0.y, g0.z, g0.w, g1.x, g1.y, g1.z, g1.w};
#pragma unroll
            for (int i = 0; i < 8; ++i)
#pragma unroll
                for (int j = 0; j < 8; ++j)
                    acc[i][j] = fmaf(av[i], bv[j], acc[i][j]);
        }
    }
    float* Cb = C + (size_t)(b0 + bb) * DD * DD;
#pragma unroll
    for (int i = 0; i < 8; ++i) {
        const size_t r = (size_t)(d0 + 8 * td + i) * DD;
        *(float4*)&Cb[r + e0 + 4 * te]      = make_float4(acc[i][0], acc[i][1], acc[i][2], acc[i][3]);
        *(float4*)&Cb[r + e0 + 64 + 4 * te] = make_float4(acc[i][4], acc[i][5], acc[i][6], acc[i][7]);
    }
    if (d0 == e0) {   // fused partial trace
        float ts = 0.f;
#pragma unroll
        for (int i = 0; i < 8; ++i) {
            const int lr = 8 * td + i;
#pragma unroll
            for (int j = 0; j < 8; ++j) {
                const int lc = (j < 4) ? (4 * te + j) : (64 + 4 * te + (j - 4));
                if (lr == lc) ts += acc[i][j];
            }
        }
        red[t] = ts;
        __syncthreads();
        for (int s = 128; s > 0; s >>= 1) {
            if (t < s) red[t] += red[t + s];
            __syncthreads();
        }
        if (t == 0) atomicAdd(&Sc[b0 + bb], red[0]);
    }
}

// ---------------- E = (D/s)^2, same 128-tile structure, K=256 ---------------
__global__ __launch_bounds__(256) void sq_kernel(const float* __restrict__ Dm,
                                                 float* __restrict__ E,
                                                 const float* __restrict__ s_in,
                                                 float* __restrict__ s_out) {
    const int id   = blockIdx.x;
    const int bb   = id & 63;            // blockId%8 == bb%8 : ping-pong L2-local
    const int tile = id >> 6;
    const int d0 = (tile >> 1) * 128, e0 = (tile & 1) * 128;
    const int t  = threadIdx.x;
    const int td = t >> 4, te = t & 15;
    const int sr = t >> 5, sc4 = (t & 31) * 4;
    __shared__ float Ad[32][128];
    __shared__ float Ae[32][128];
    __shared__ float red[256];
    float acc[8][8] = {};
    const float* Db = Dm + (size_t)bb * DD * DD;
    const float s = s_in[bb];
    const float inv = 1.f / (s * s);
    for (int kb = 0; kb < DD; kb += 32) {
        float4 ra[4], rb[4];
#pragma unroll
        for (int p = 0; p < 4; ++p) {
            const size_t row = (size_t)(kb + p * 8 + sr) * DD;
            ra[p] = *(const float4*)&Db[row + d0 + sc4];
            rb[p] = *(const float4*)&Db[row + e0 + sc4];
        }
        __syncthreads();
#pragma unroll
        for (int p = 0; p < 4; ++p) {
            *(float4*)&Ad[p * 8 + sr][sc4] = ra[p];
            *(float4*)&Ae[p * 8 + sr][sc4] = rb[p];
        }
        __syncthreads();
#pragma unroll 4
        for (int k = 0; k < 32; ++k) {
            const float4 a0 = *(const float4*)&Ad[k][8 * td];
            const float4 a1 = *(const float4*)&Ad[k][8 * td + 4];
            const float4 g0 = *(const float4*)&Ae[k][4 * te];
            const float4 g1 = *(const float4*)&Ae[k][64 + 4 * te];
            const float av[8] = {a0.x, a0.y, a0.z, a0.w, a1.x, a1.y, a1.z, a1.w};
            const float bv[8] = {g0.x, g0.y, g0.z, g0.w, g1.x, g1.y, g1.z, g1.w};
#pragma unroll
            for (int i = 0; i < 8; ++i)
#pragma unroll
                for (int j = 0; j < 8; ++j)
                    acc[i][j] = fmaf(av[i], bv[j], acc[i][j]);
        }
    }
#pragma unroll
    for (int i = 0; i < 8; ++i)
#pragma unroll
        for (int j = 0; j < 8; ++j)
            acc[i][j] *= inv;
    float* Eb = E + (size_t)bb * DD * DD;
#pragma unroll
    for (int i = 0; i < 8; ++i) {
        const size_t r = (size_t)(d0 + 8 * td + i) * DD;
        *(float4*)&Eb[r + e0 + 4 * te]      = make_float4(acc[i][0], acc[i][1], acc[i][2], acc[i][3]);
        *(float4*)&Eb[r + e0 + 64 + 4 * te] = make_float4(acc[i][4], acc[i][5], acc[i][6], acc[i][7]);
    }
    if (d0 == e0) {
        float ts = 0.f;
#pragma unroll
        for (int i = 0; i < 8; ++i) {
            const int lr = 8 * td + i;
#pragma unroll
            for (int j = 0; j < 8; ++j) {
                const int lc = (j < 4) ? (4 * te + j) : (64 + 4 * te + (j - 4));
                if (lr == lc) ts += acc[i][j];
            }
        }
        red[t] = ts;
        __syncthreads();
        for (int s = 128; s > 0; s >>= 1) {
            if (t < s) red[t] += red[t + s];
            __syncthreads();
        }
        if (t == 0) atomicAdd(&s_out[bb], red[0]);
    }
}

// ------- finish: column start + NPI matvecs (no renorm; lambda1 ~ 1) --------
__global__ void finish_kernel(const float* __restrict__ Dm, float* __restrict__ out) {
    const int b = blockIdx.x, t = threadIdx.x;
    const float* Db = Dm + (size_t)b * DD * DD;
    __shared__ float vs[DD];
    __shared__ float red[DD];
    __shared__ int   ridx[DD];
    red[t] = Db[(size_t)t * DD + t];
    ridx[t] = t;
    __syncthreads();
    for (int s = 128; s > 0; s >>= 1) {
        if (t < s && red[t + s] > red[t]) { red[t] = red[t + s]; ridx[t] = ridx[t + s]; }
        __syncthreads();
    }
    const int jmax0 = ridx[0];
    __syncthreads();
    float v = Db[(size_t)jmax0 * DD + t];   // symmetric: column == row
    for (int it = 0; it < NPI; ++it) {
        vs[t] = v;
        __syncthreads();
        float a = 0.f;
        const float* row = Db + (size_t)t * DD;
#pragma unroll 8
        for (int j = 0; j < DD; j += 4) {
            float4 d4 = *(const float4*)&row[j];
            a = fmaf(d4.x, vs[j], a);
            a = fmaf(d4.y, vs[j + 1], a);
            a = fmaf(d4.z, vs[j + 2], a);
            a = fmaf(d4.w, vs[j + 3], a);
        }
        __syncthreads();
        v = a;
    }
    vs[t] = v;
    red[t] = v * v;
    __syncthreads();
    for (int s = 128; s > 0; s >>= 1) {
        if (t < s) red[t] += red[t + s];
        __syncthreads();
    }
    const float nrm = sqrtf(red[0]);
    __syncthreads();
    red[t] = fabsf(v);
    ridx[t] = t;
    __syncthreads();
    for (int s = 128; s > 0; s >>= 1) {
        if (t < s && red[t + s] > red[t]) { red[t] = red[t + s]; ridx[t] = ridx[t + s]; }
        __syncthreads();
    }
    const float sgn = (vs[ridx[0]] < 0.f) ? -1.f : 1.f;
    out[(size_t)b * DD + t] = sgn * v / nrm;
}

extern "C" void kernel_launch(void* const* d_in, const int* in_sizes, int n_in,
                              void* d_out, int out_size, void* d_ws, size_t ws_size,
                              hipStream_t stream) {
    const float* caps = (const float*)d_in[0];   // (64, 2048, 16)
    const float* W    = (const float*)d_in[1];   // (2048, 16, 256)
    float* out = (float*)d_out;                  // (64, 256)
    float* ws  = (float*)d_ws;

    // pick batch-group size from ws_size; 16-group = 50.3 MB (proven R3 fit)
    int gbatch = 64, bshift = 6;
    if (ws_size < ((size_t)64 * IC * DD + 4194304 + 2048) * 4) { gbatch = 32; bshift = 5; }
    if (ws_size < ((size_t)32 * IC * DD + 4194304 + 2048) * 4) { gbatch = 16; bshift = 4; }

    const size_t usz = (size_t)gbatch * IC * DD;
    float* U  = ws;
    float* Cb = ws + usz;
    float* Sc = ws + usz + 4194304;
    float* Eb = ws;                    // overlay: U dead once sq phase starts

    hipMemsetAsync(Sc, 0, 2048 * sizeof(float), stream);

    const int ngrp = NB / gbatch;
    for (int g = 0; g < ngrp; ++g) {
        if (gbatch == 64)
            u_kernel<64><<<IC, 256, 0, stream>>>(caps, W, U, g * gbatch);
        else if (gbatch == 32)
            u_kernel<32><<<IC, 256, 0, stream>>>(caps, W, U, g * gbatch);
        else
            u_kernel<16><<<IC, 256, 0, stream>>>(caps, W, U, g * gbatch);
        c_kernel<<<4 * gbatch, 256, 0, stream>>>(U, Cb, Sc, g * gbatch, gbatch - 1, bshift);
    }

    float* ping = Cb;
    float* pong = Eb;
    for (int it = 0; it < NSQ; ++it) {
        sq_kernel<<<256, 256, 0, stream>>>(ping, pong, Sc + it * 64, Sc + (it + 1) * 64);
        float* tmp = ping; ping = pong; pong = tmp;
    }

    finish_kernel<<<NB, 256, 0, stream>>>(ping, out);  // NSQ odd -> ping == Eb
}

// Round 5
// 942.939 us; speedup vs baseline: 1.3544x; 1.1071x over previous
//
#include <hip/hip_runtime.h>

#define NB  64
#define IC  2048
#define ID  16
#define DD  256
#define NSQ 11    // matrix squarings
#define NPI 7     // finish matvecs: exponent 2^11 * 8 = 16384 (verified R3/R4)

// ---------------- stage 1: u[b,c,:] = x[b,c,:] @ W_c (all GBATCH batches) ---
template<int GBATCH>
__global__ __launch_bounds__(256, 2) void u_kernel(const float* __restrict__ caps,
                                                   const float* __restrict__ W,
                                                   float* __restrict__ U, int b0) {
    const int c = blockIdx.x;
    const int t = threadIdx.x;
    __shared__ float xsT[ID][GBATCH];     // transposed: float4 reads over b
    if (t < GBATCH * 4) {
        const int b = t >> 2, q = (t & 3) * 4;
        const float4 x4 = *(const float4*)&caps[((size_t)(b0 + b) * IC + c) * ID + q];
        xsT[q + 0][b] = x4.x; xsT[q + 1][b] = x4.y;
        xsT[q + 2][b] = x4.z; xsT[q + 3][b] = x4.w;
    }
    float w[ID];
#pragma unroll
    for (int i = 0; i < ID; ++i) w[i] = W[((size_t)c * ID + i) * DD + t];
    __syncthreads();
    float acc[GBATCH] = {};
#pragma unroll 4
    for (int i = 0; i < ID; ++i) {
#pragma unroll
        for (int bq = 0; bq < GBATCH / 4; ++bq) {
            const float4 xv = *(const float4*)&xsT[i][4 * bq];
            acc[4 * bq + 0] = fmaf(xv.x, w[i], acc[4 * bq + 0]);
            acc[4 * bq + 1] = fmaf(xv.y, w[i], acc[4 * bq + 1]);
            acc[4 * bq + 2] = fmaf(xv.z, w[i], acc[4 * bq + 2]);
            acc[4 * bq + 3] = fmaf(xv.w, w[i], acc[4 * bq + 3]);
        }
    }
#pragma unroll
    for (int b = 0; b < GBATCH; ++b)
        U[((size_t)b * IC + c) * DD + t] = acc[b];
}

// ------- stage 2: partial C, 128x128 tile, 8x8 micro, K=1024 per block ------
// id = (tile*2+kch)*gbatch + bb  -> low bits = bb : tiles of a batch co-XCD
__global__ __launch_bounds__(256, 2) void c_kernel(const float* __restrict__ U,
                                                   float* __restrict__ P0,
                                                   float* __restrict__ P1,
                                                   float* __restrict__ Sc,
                                                   int b0, int bmask, int bshift) {
    const int id   = blockIdx.x;
    const int bb   = id & bmask;
    const int tk   = id >> bshift;       // 0..7
    const int tile = tk >> 1, kch = tk & 1;
    const int d0 = (tile >> 1) * 128, e0 = (tile & 1) * 128;
    const int t  = threadIdx.x;
    const int td = t >> 4, te = t & 15;
    const int sr = t >> 5, sc4 = (t & 31) * 4;
    __shared__ float Ad[32][128];
    __shared__ float Ae[32][128];
    __shared__ float red[256];
    float acc[8][8] = {};
    const float* Ub = U + (size_t)bb * IC * DD;
    const int k0 = kch * (IC / 2);
    for (int kb = k0; kb < k0 + IC / 2; kb += 32) {
        float4 ra[4], rb[4];
#pragma unroll
        for (int p = 0; p < 4; ++p) {
            const size_t row = (size_t)(kb + p * 8 + sr) * DD;
            ra[p] = *(const float4*)&Ub[row + d0 + sc4];
            rb[p] = *(const float4*)&Ub[row + e0 + sc4];
        }
        __syncthreads();
#pragma unroll
        for (int p = 0; p < 4; ++p) {
            *(float4*)&Ad[p * 8 + sr][sc4] = ra[p];
            *(float4*)&Ae[p * 8 + sr][sc4] = rb[p];
        }
        __syncthreads();
#pragma unroll 4
        for (int k = 0; k < 32; ++k) {
            const float4 a0 = *(const float4*)&Ad[k][8 * td];
            const float4 a1 = *(const float4*)&Ad[k][8 * td + 4];
            const float4 g0 = *(const float4*)&Ae[k][4 * te];        // 2-way: free
            const float4 g1 = *(const float4*)&Ae[k][64 + 4 * te];
            const float av[8] = {a0.x, a0.y, a0.z, a0.w, a1.x, a1.y, a1.z, a1.w};
            const float bv[8] = {g0.x, g0.y, g0.z, g0.w, g1.x, g1.y, g1.z, g1.w};
#pragma unroll
            for (int i = 0; i < 8; ++i)
#pragma unroll
                for (int j = 0; j < 8; ++j)
                    acc[i][j] = fmaf(av[i], bv[j], acc[i][j]);
        }
    }
    float* Pb = (kch ? P1 : P0) + (size_t)(b0 + bb) * DD * DD;
#pragma unroll
    for (int i = 0; i < 8; ++i) {
        const size_t r = (size_t)(d0 + 8 * td + i) * DD;
        *(float4*)&Pb[r + e0 + 4 * te]      = make_float4(acc[i][0], acc[i][1], acc[i][2], acc[i][3]);
        *(float4*)&Pb[r + e0 + 64 + 4 * te] = make_float4(acc[i][4], acc[i][5], acc[i][6], acc[i][7]);
    }
    if (d0 == e0) {   // fused partial trace (both k-chunks contribute)
        float ts = 0.f;
#pragma unroll
        for (int i = 0; i < 8; ++i) {
            const int lr = 8 * td + i;
#pragma unroll
            for (int j = 0; j < 8; ++j) {
                const int lc = (j < 4) ? (4 * te + j) : (64 + 4 * te + (j - 4));
                if (lr == lc) ts += acc[i][j];
            }
        }
        red[t] = ts;
        __syncthreads();
        for (int s = 128; s > 0; s >>= 1) {
            if (t < s) red[t] += red[t + s];
            __syncthreads();
        }
        if (t == 0) atomicAdd(&Sc[b0 + bb], red[0]);
    }
}

// --------- E = (D/s)^2, 128-tile; ADD2: D = D0 + D1 (partial fold) ----------
template<bool ADD2>
__global__ __launch_bounds__(256, 2) void sq_kernel(const float* __restrict__ D0,
                                                    const float* __restrict__ D1,
                                                    float* __restrict__ E,
                                                    const float* __restrict__ s_in,
                                                    float* __restrict__ s_out) {
    const int id   = blockIdx.x;
    const int bb   = id & 63;            // low bits = batch : L2-local
    const int tile = id >> 6;
    const int d0 = (tile >> 1) * 128, e0 = (tile & 1) * 128;
    const int t  = threadIdx.x;
    const int td = t >> 4, te = t & 15;
    const int sr = t >> 5, sc4 = (t & 31) * 4;
    __shared__ float Ad[32][128];
    __shared__ float Ae[32][128];
    __shared__ float red[256];
    float acc[8][8] = {};
    const size_t mb = (size_t)bb * DD * DD;
    const float s = s_in[bb];
    const float inv = 1.f / (s * s);
    for (int kb = 0; kb < DD; kb += 32) {
        float4 ra[4], rb[4];
#pragma unroll
        for (int p = 0; p < 4; ++p) {
            const size_t row = mb + (size_t)(kb + p * 8 + sr) * DD;
            ra[p] = *(const float4*)&D0[row + d0 + sc4];
            rb[p] = *(const float4*)&D0[row + e0 + sc4];
            if (ADD2) {
                const float4 xa = *(const float4*)&D1[row + d0 + sc4];
                const float4 xb = *(const float4*)&D1[row + e0 + sc4];
                ra[p].x += xa.x; ra[p].y += xa.y; ra[p].z += xa.z; ra[p].w += xa.w;
                rb[p].x += xb.x; rb[p].y += xb.y; rb[p].z += xb.z; rb[p].w += xb.w;
            }
        }
        __syncthreads();
#pragma unroll
        for (int p = 0; p < 4; ++p) {
            *(float4*)&Ad[p * 8 + sr][sc4] = ra[p];
            *(float4*)&Ae[p * 8 + sr][sc4] = rb[p];
        }
        __syncthreads();
#pragma unroll 4
        for (int k = 0; k < 32; ++k) {
            const float4 a0 = *(const float4*)&Ad[k][8 * td];
            const float4 a1 = *(const float4*)&Ad[k][8 * td + 4];
            const float4 g0 = *(const float4*)&Ae[k][4 * te];
            const float4 g1 = *(const float4*)&Ae[k][64 + 4 * te];
            const float av[8] = {a0.x, a0.y, a0.z, a0.w, a1.x, a1.y, a1.z, a1.w};
            const float bv[8] = {g0.x, g0.y, g0.z, g0.w, g1.x, g1.y, g1.z, g1.w};
#pragma unroll
            for (int i = 0; i < 8; ++i)
#pragma unroll
                for (int j = 0; j < 8; ++j)
                    acc[i][j] = fmaf(av[i], bv[j], acc[i][j]);
        }
    }
#pragma unroll
    for (int i = 0; i < 8; ++i)
#pragma unroll
        for (int j = 0; j < 8; ++j)
            acc[i][j] *= inv;
    float* Eb = E + mb;
#pragma unroll
    for (int i = 0; i < 8; ++i) {
        const size_t r = (size_t)(d0 + 8 * td + i) * DD;
        *(float4*)&Eb[r + e0 + 4 * te]      = make_float4(acc[i][0], acc[i][1], acc[i][2], acc[i][3]);
        *(float4*)&Eb[r + e0 + 64 + 4 * te] = make_float4(acc[i][4], acc[i][5], acc[i][6], acc[i][7]);
    }
    if (d0 == e0) {
        float ts = 0.f;
#pragma unroll
        for (int i = 0; i < 8; ++i) {
            const int lr = 8 * td + i;
#pragma unroll
            for (int j = 0; j < 8; ++j) {
                const int lc = (j < 4) ? (4 * te + j) : (64 + 4 * te + (j - 4));
                if (lr == lc) ts += acc[i][j];
            }
        }
        red[t] = ts;
        __syncthreads();
        for (int s = 128; s > 0; s >>= 1) {
            if (t < s) red[t] += red[t + s];
            __syncthreads();
        }
        if (t == 0) atomicAdd(&s_out[bb], red[0]);
    }
}

// ------- finish: column start + NPI matvecs (no renorm; lambda1 ~ 1) --------
__global__ __launch_bounds__(256, 2) void finish_kernel(const float* __restrict__ Dm,
                                                        float* __restrict__ out) {
    const int b = blockIdx.x, t = threadIdx.x;
    const float* Db = Dm + (size_t)b * DD * DD;
    __shared__ float vs[DD];
    __shared__ float red[DD];
    __shared__ int   ridx[DD];
    red[t] = Db[(size_t)t * DD + t];
    ridx[t] = t;
    __syncthreads();
    for (int s = 128; s > 0; s >>= 1) {
        if (t < s && red[t + s] > red[t]) { red[t] = red[t + s]; ridx[t] = ridx[t + s]; }
        __syncthreads();
    }
    const int jmax0 = ridx[0];
    __syncthreads();
    float v = Db[(size_t)jmax0 * DD + t];   // symmetric: column == row
    for (int it = 0; it < NPI; ++it) {
        vs[t] = v;
        __syncthreads();
        float a = 0.f;
        const float* row = Db + (size_t)t * DD;
#pragma unroll 8
        for (int j = 0; j < DD; j += 4) {
            float4 d4 = *(const float4*)&row[j];
            a = fmaf(d4.x, vs[j], a);
            a = fmaf(d4.y, vs[j + 1], a);
            a = fmaf(d4.z, vs[j + 2], a);
            a = fmaf(d4.w, vs[j + 3], a);
        }
        __syncthreads();
        v = a;
    }
    vs[t] = v;
    red[t] = v * v;
    __syncthreads();
    for (int s = 128; s > 0; s >>= 1) {
        if (t < s) red[t] += red[t + s];
        __syncthreads();
    }
    const float nrm = sqrtf(red[0]);
    __syncthreads();
    red[t] = fabsf(v);
    ridx[t] = t;
    __syncthreads();
    for (int s = 128; s > 0; s >>= 1) {
        if (t < s && red[t + s] > red[t]) { red[t] = red[t + s]; ridx[t] = ridx[t + s]; }
        __syncthreads();
    }
    const float sgn = (vs[ridx[0]] < 0.f) ? -1.f : 1.f;
    out[(size_t)b * DD + t] = sgn * v / nrm;
}

extern "C" void kernel_launch(void* const* d_in, const int* in_sizes, int n_in,
                              void* d_out, int out_size, void* d_ws, size_t ws_size,
                              hipStream_t stream) {
    const float* caps = (const float*)d_in[0];   // (64, 2048, 16)
    const float* W    = (const float*)d_in[1];   // (2048, 16, 256)
    float* out = (float*)d_out;                  // (64, 256)
    float* ws  = (float*)d_ws;

    // pick batch-group size from ws_size (need U + Cb + P1 + Sc)
    int gbatch = 64, bshift = 6;
    if (ws_size < ((size_t)64 * IC * DD + 8388608 + 2048) * 4) { gbatch = 32; bshift = 5; }
    if (ws_size < ((size_t)32 * IC * DD + 8388608 + 2048) * 4) { gbatch = 16; bshift = 4; }

    const size_t usz = (size_t)gbatch * IC * DD;
    float* U  = ws;
    float* Cb = ws + usz;                // P0
    float* P1 = ws + usz + 4194304;
    float* Sc = ws + usz + 8388608;
    float* Eb = ws;                      // overlay: U dead once sq phase starts

    hipMemsetAsync(Sc, 0, 2048 * sizeof(float), stream);

    const int ngrp = NB / gbatch;
    for (int g = 0; g < ngrp; ++g) {
        if (gbatch == 64)
            u_kernel<64><<<IC, 256, 0, stream>>>(caps, W, U, g * gbatch);
        else if (gbatch == 32)
            u_kernel<32><<<IC, 256, 0, stream>>>(caps, W, U, g * gbatch);
        else
            u_kernel<16><<<IC, 256, 0, stream>>>(caps, W, U, g * gbatch);
        c_kernel<<<8 * gbatch, 256, 0, stream>>>(U, Cb, P1, Sc, g * gbatch, gbatch - 1, bshift);
    }

    // eigen: first squaring folds P0+P1; then 10 plain squarings
    float* ping = Cb;
    float* pong = Eb;
    sq_kernel<true><<<256, 256, 0, stream>>>(ping, P1, pong, Sc, Sc + 64);
    { float* tmp = ping; ping = pong; pong = tmp; }
    for (int it = 1; it < NSQ; ++it) {
        sq_kernel<false><<<256, 256, 0, stream>>>(ping, nullptr, pong, Sc + it * 64, Sc + (it + 1) * 64);
        float* tmp = ping; ping = pong; pong = tmp;
    }

    finish_kernel<<<NB, 256, 0, stream>>>(ping, out);  // NSQ odd -> ping == Eb
}

// Round 6
// 777.660 us; speedup vs baseline: 1.6423x; 1.2125x over previous
//
#include <hip/hip_runtime.h>

#define NB  64
#define IC  2048
#define ID  16
#define DD  256
#define DDSQ (DD * DD)        // 65536
#define PB  (DDSQ * NB)       // 4,194,304 floats per full-batch matrix buffer
#define NSQ 11                // matrix squarings
#define NPI 7                 // finish matvecs: exponent 2^11 * 8 = 16384

#define FMA4(c, s, v) { (c).x = fmaf((s), (v).x, (c).x); (c).y = fmaf((s), (v).y, (c).y); \
                        (c).z = fmaf((s), (v).z, (c).z); (c).w = fmaf((s), (v).w, (c).w); }

__device__ inline float f4c(const float4& v, int j) {
    return j == 0 ? v.x : j == 1 ? v.y : j == 2 ? v.z : v.w;
}

// ---------------- stage 1: u[b,c,:] = x[b,c,:] @ W_c (all GBATCH batches) ---
template<int GBATCH>
__global__ __launch_bounds__(256, 2) void u_kernel(const float* __restrict__ caps,
                                                   const float* __restrict__ W,
                                                   float* __restrict__ U, int b0) {
    const int c = blockIdx.x;
    const int t = threadIdx.x;
    __shared__ float xsT[ID][GBATCH];
    if (t < GBATCH * 4) {
        const int b = t >> 2, q = (t & 3) * 4;
        const float4 x4 = *(const float4*)&caps[((size_t)(b0 + b) * IC + c) * ID + q];
        xsT[q + 0][b] = x4.x; xsT[q + 1][b] = x4.y;
        xsT[q + 2][b] = x4.z; xsT[q + 3][b] = x4.w;
    }
    float w[ID];
#pragma unroll
    for (int i = 0; i < ID; ++i) w[i] = W[((size_t)c * ID + i) * DD + t];
    __syncthreads();
    float acc[GBATCH] = {};
#pragma unroll 4
    for (int i = 0; i < ID; ++i) {
#pragma unroll
        for (int bq = 0; bq < GBATCH / 4; ++bq) {
            const float4 xv = *(const float4*)&xsT[i][4 * bq];
            acc[4 * bq + 0] = fmaf(xv.x, w[i], acc[4 * bq + 0]);
            acc[4 * bq + 1] = fmaf(xv.y, w[i], acc[4 * bq + 1]);
            acc[4 * bq + 2] = fmaf(xv.z, w[i], acc[4 * bq + 2]);
            acc[4 * bq + 3] = fmaf(xv.w, w[i], acc[4 * bq + 3]);
        }
    }
#pragma unroll
    for (int b = 0; b < GBATCH; ++b)
        U[((size_t)b * IC + c) * DD + t] = acc[b];
}

// ------- stage 2: partial C, 128x128 tile, 8x8 micro (float4 acc), K=1024 ---
__global__ __attribute__((amdgpu_flat_work_group_size(256, 256),
                          amdgpu_waves_per_eu(2, 2)))
void c_kernel(const float* __restrict__ U,
              float* __restrict__ P0, float* __restrict__ P1,
              float* __restrict__ Sc, int b0, int bmask, int bshift) {
    const int id   = blockIdx.x;
    const int bb   = id & bmask;
    const int tk   = id >> bshift;       // 0..7
    const int tile = tk >> 1, kch = tk & 1;
    const int d0 = (tile >> 1) * 128, e0 = (tile & 1) * 128;
    const int t  = threadIdx.x;
    const int td = t >> 4, te = t & 15;
    const int sr = t >> 5, sc4 = (t & 31) * 4;
    __shared__ float Ad[32][128];
    __shared__ float Ae[32][128];
    __shared__ float red[256];
    float4 cl[8], ch[8];                 // 16 float4 accumulators (promotable)
#pragma unroll
    for (int i = 0; i < 8; ++i) {
        cl[i] = make_float4(0.f, 0.f, 0.f, 0.f);
        ch[i] = make_float4(0.f, 0.f, 0.f, 0.f);
    }
    const float* Ub = U + (size_t)bb * IC * DD;
    const int k0 = kch * (IC / 2);
    for (int kb = k0; kb < k0 + IC / 2; kb += 32) {
        float4 ra[4], rb[4];
#pragma unroll
        for (int p = 0; p < 4; ++p) {
            const size_t row = (size_t)(kb + p * 8 + sr) * DD;
            ra[p] = *(const float4*)&Ub[row + d0 + sc4];
            rb[p] = *(const float4*)&Ub[row + e0 + sc4];
        }
        __syncthreads();
#pragma unroll
        for (int p = 0; p < 4; ++p) {
            *(float4*)&Ad[p * 8 + sr][sc4] = ra[p];
            *(float4*)&Ae[p * 8 + sr][sc4] = rb[p];
        }
        __syncthreads();
#pragma unroll 4
        for (int k = 0; k < 32; ++k) {
            const float4 aL = *(const float4*)&Ad[k][8 * td];
            const float4 aH = *(const float4*)&Ad[k][8 * td + 4];
            const float4 bL = *(const float4*)&Ae[k][4 * te];
            const float4 bH = *(const float4*)&Ae[k][64 + 4 * te];
            FMA4(cl[0], aL.x, bL); FMA4(ch[0], aL.x, bH);
            FMA4(cl[1], aL.y, bL); FMA4(ch[1], aL.y, bH);
            FMA4(cl[2], aL.z, bL); FMA4(ch[2], aL.z, bH);
            FMA4(cl[3], aL.w, bL); FMA4(ch[3], aL.w, bH);
            FMA4(cl[4], aH.x, bL); FMA4(ch[4], aH.x, bH);
            FMA4(cl[5], aH.y, bL); FMA4(ch[5], aH.y, bH);
            FMA4(cl[6], aH.z, bL); FMA4(ch[6], aH.z, bH);
            FMA4(cl[7], aH.w, bL); FMA4(ch[7], aH.w, bH);
        }
    }
    float* Pb = (kch ? P1 : P0) + (size_t)(b0 + bb) * DDSQ;
#pragma unroll
    for (int i = 0; i < 8; ++i) {
        const size_t r = (size_t)(d0 + 8 * td + i) * DD;
        *(float4*)&Pb[r + e0 + 4 * te]      = cl[i];
        *(float4*)&Pb[r + e0 + 64 + 4 * te] = ch[i];
    }
    if (d0 == e0) {   // fused partial trace (both k-chunks contribute)
        float ts = 0.f;
#pragma unroll
        for (int i = 0; i < 8; ++i) {
            const int lr = 8 * td + i;
            const int dl = lr - 4 * te;
            if (dl >= 0 && dl < 4) ts += f4c(cl[i], dl);
            const int dh = lr - 64 - 4 * te;
            if (dh >= 0 && dh < 4) ts += f4c(ch[i], dh);
        }
        red[t] = ts;
        __syncthreads();
        for (int s = 128; s > 0; s >>= 1) {
            if (t < s) red[t] += red[t + s];
            __syncthreads();
        }
        if (t == 0) atomicAdd(&Sc[b0 + bb], red[0]);
    }
}

// ---- E = (D/s)^2 with D = D0+D1 (fold), k-split 2-way output (E0,E1) ------
__global__ __attribute__((amdgpu_flat_work_group_size(256, 256),
                          amdgpu_waves_per_eu(2, 2)))
void sq_kernel(const float* __restrict__ D0, const float* __restrict__ D1,
               float* __restrict__ E0, float* __restrict__ E1,
               const float* __restrict__ s_in, float* __restrict__ s_out) {
    const int id   = blockIdx.x;          // 512 blocks
    const int bb   = id & 63;             // low bits = batch : L2-local
    const int tk   = id >> 6;             // 0..7
    const int tile = tk >> 1, kch = tk & 1;
    const int d0 = (tile >> 1) * 128, e0 = (tile & 1) * 128;
    const int t  = threadIdx.x;
    const int td = t >> 4, te = t & 15;
    const int sr = t >> 5, sc4 = (t & 31) * 4;
    __shared__ float Ad[32][128];
    __shared__ float Ae[32][128];
    __shared__ float red[256];
    float4 cl[8], ch[8];
#pragma unroll
    for (int i = 0; i < 8; ++i) {
        cl[i] = make_float4(0.f, 0.f, 0.f, 0.f);
        ch[i] = make_float4(0.f, 0.f, 0.f, 0.f);
    }
    const size_t mb = (size_t)bb * DDSQ;
    const float s = s_in[bb];
    const float inv = 1.f / (s * s);
    const int k0 = kch * (DD / 2);
    for (int kb = k0; kb < k0 + DD / 2; kb += 32) {
        float4 ra[4], rb[4];
#pragma unroll
        for (int p = 0; p < 4; ++p) {
            const size_t row = mb + (size_t)(kb + p * 8 + sr) * DD;
            ra[p] = *(const float4*)&D0[row + d0 + sc4];
            rb[p] = *(const float4*)&D0[row + e0 + sc4];
            const float4 xa = *(const float4*)&D1[row + d0 + sc4];
            const float4 xb = *(const float4*)&D1[row + e0 + sc4];
            ra[p].x += xa.x; ra[p].y += xa.y; ra[p].z += xa.z; ra[p].w += xa.w;
            rb[p].x += xb.x; rb[p].y += xb.y; rb[p].z += xb.z; rb[p].w += xb.w;
        }
        __syncthreads();
#pragma unroll
        for (int p = 0; p < 4; ++p) {
            *(float4*)&Ad[p * 8 + sr][sc4] = ra[p];
            *(float4*)&Ae[p * 8 + sr][sc4] = rb[p];
        }
        __syncthreads();
#pragma unroll 4
        for (int k = 0; k < 32; ++k) {
            const float4 aL = *(const float4*)&Ad[k][8 * td];
            const float4 aH = *(const float4*)&Ad[k][8 * td + 4];
            const float4 bL = *(const float4*)&Ae[k][4 * te];
            const float4 bH = *(const float4*)&Ae[k][64 + 4 * te];
            FMA4(cl[0], aL.x, bL); FMA4(ch[0], aL.x, bH);
            FMA4(cl[1], aL.y, bL); FMA4(ch[1], aL.y, bH);
            FMA4(cl[2], aL.z, bL); FMA4(ch[2], aL.z, bH);
            FMA4(cl[3], aL.w, bL); FMA4(ch[3], aL.w, bH);
            FMA4(cl[4], aH.x, bL); FMA4(ch[4], aH.x, bH);
            FMA4(cl[5], aH.y, bL); FMA4(ch[5], aH.y, bH);
            FMA4(cl[6], aH.z, bL); FMA4(ch[6], aH.z, bH);
            FMA4(cl[7], aH.w, bL); FMA4(ch[7], aH.w, bH);
        }
    }
#pragma unroll
    for (int i = 0; i < 8; ++i) {
        cl[i].x *= inv; cl[i].y *= inv; cl[i].z *= inv; cl[i].w *= inv;
        ch[i].x *= inv; ch[i].y *= inv; ch[i].z *= inv; ch[i].w *= inv;
    }
    float* Eb = (kch ? E1 : E0) + mb;
#pragma unroll
    for (int i = 0; i < 8; ++i) {
        const size_t r = (size_t)(d0 + 8 * td + i) * DD;
        *(float4*)&Eb[r + e0 + 4 * te]      = cl[i];
        *(float4*)&Eb[r + e0 + 64 + 4 * te] = ch[i];
    }
    if (d0 == e0) {
        float ts = 0.f;
#pragma unroll
        for (int i = 0; i < 8; ++i) {
            const int lr = 8 * td + i;
            const int dl = lr - 4 * te;
            if (dl >= 0 && dl < 4) ts += f4c(cl[i], dl);
            const int dh = lr - 64 - 4 * te;
            if (dh >= 0 && dh < 4) ts += f4c(ch[i], dh);
        }
        red[t] = ts;
        __syncthreads();
        for (int s = 128; s > 0; s >>= 1) {
            if (t < s) red[t] += red[t + s];
            __syncthreads();
        }
        if (t == 0) atomicAdd(&s_out[bb], red[0]);
    }
}

// -- finish: D = D0+D1; column start + NPI matvecs (no renorm; lambda1 ~ 1) --
__global__ __launch_bounds__(256, 2) void finish_kernel(const float* __restrict__ D0,
                                                        const float* __restrict__ D1,
                                                        float* __restrict__ out) {
    const int b = blockIdx.x, t = threadIdx.x;
    const size_t mb = (size_t)b * DDSQ;
    __shared__ float vs[DD];
    __shared__ float red[DD];
    __shared__ int   ridx[DD];
    red[t] = D0[mb + (size_t)t * DD + t] + D1[mb + (size_t)t * DD + t];
    ridx[t] = t;
    __syncthreads();
    for (int s = 128; s > 0; s >>= 1) {
        if (t < s && red[t + s] > red[t]) { red[t] = red[t + s]; ridx[t] = ridx[t + s]; }
        __syncthreads();
    }
    const int jmax0 = ridx[0];
    __syncthreads();
    float v = D0[mb + (size_t)jmax0 * DD + t] + D1[mb + (size_t)jmax0 * DD + t];
    for (int it = 0; it < NPI; ++it) {
        vs[t] = v;
        __syncthreads();
        float a = 0.f;
        const float* r0 = D0 + mb + (size_t)t * DD;
        const float* r1 = D1 + mb + (size_t)t * DD;
#pragma unroll 8
        for (int j = 0; j < DD; j += 4) {
            const float4 d4 = *(const float4*)&r0[j];
            const float4 e4 = *(const float4*)&r1[j];
            a = fmaf(d4.x + e4.x, vs[j],     a);
            a = fmaf(d4.y + e4.y, vs[j + 1], a);
            a = fmaf(d4.z + e4.z, vs[j + 2], a);
            a = fmaf(d4.w + e4.w, vs[j + 3], a);
        }
        __syncthreads();
        v = a;
    }
    vs[t] = v;
    red[t] = v * v;
    __syncthreads();
    for (int s = 128; s > 0; s >>= 1) {
        if (t < s) red[t] += red[t + s];
        __syncthreads();
    }
    const float nrm = sqrtf(red[0]);
    __syncthreads();
    red[t] = fabsf(v);
    ridx[t] = t;
    __syncthreads();
    for (int s = 128; s > 0; s >>= 1) {
        if (t < s && red[t + s] > red[t]) { red[t] = red[t + s]; ridx[t] = ridx[t + s]; }
        __syncthreads();
    }
    const float sgn = (vs[ridx[0]] < 0.f) ? -1.f : 1.f;
    out[(size_t)b * DD + t] = sgn * v / nrm;
}

extern "C" void kernel_launch(void* const* d_in, const int* in_sizes, int n_in,
                              void* d_out, int out_size, void* d_ws, size_t ws_size,
                              hipStream_t stream) {
    const float* caps = (const float*)d_in[0];   // (64, 2048, 16)
    const float* W    = (const float*)d_in[1];   // (2048, 16, 256)
    float* out = (float*)d_out;                  // (64, 256)
    float* ws  = (float*)d_ws;

    int gbatch = 64, bshift = 6;
    if (ws_size < ((size_t)64 * IC * DD + 2 * PB + 2048) * 4) { gbatch = 32; bshift = 5; }
    if (ws_size < ((size_t)32 * IC * DD + 2 * PB + 2048) * 4) { gbatch = 16; bshift = 4; }

    const size_t usz = (size_t)gbatch * IC * DD;
    float* U  = ws;
    float* A0 = ws + usz;            // pair A (c_kernel output)
    float* A1 = ws + usz + PB;
    float* Sc = ws + usz + 2 * PB;
    float* B0 = ws;                  // pair B overlays U (dead after c phase)
    float* B1 = ws + PB;

    hipMemsetAsync(Sc, 0, 2048 * sizeof(float), stream);

    const int ngrp = NB / gbatch;
    for (int g = 0; g < ngrp; ++g) {
        if (gbatch == 64)
            u_kernel<64><<<IC, 256, 0, stream>>>(caps, W, U, g * gbatch);
        else if (gbatch == 32)
            u_kernel<32><<<IC, 256, 0, stream>>>(caps, W, U, g * gbatch);
        else
            u_kernel<16><<<IC, 256, 0, stream>>>(caps, W, U, g * gbatch);
        c_kernel<<<8 * gbatch, 256, 0, stream>>>(U, A0, A1, Sc, g * gbatch, gbatch - 1, bshift);
    }

    float *p0 = A0, *p1 = A1, *q0 = B0, *q1 = B1;
    for (int it = 0; it < NSQ; ++it) {
        sq_kernel<<<512, 256, 0, stream>>>(p0, p1, q0, q1, Sc + it * 64, Sc + (it + 1) * 64);
        float* t0 = p0; float* t1 = p1;
        p0 = q0; p1 = q1; q0 = t0; q1 = t1;
    }

    finish_kernel<<<NB, 256, 0, stream>>>(p0, p1, out);
}